// Round 17
// baseline (260.231 us; speedup 1.0000x reference)
//
#include <hip/hip_runtime.h>
#include <hip/hip_bf16.h>

#define DIMK 3
#define NPTS 30
#define KK   181
#define PP   24360
#define DEMB 190
#define VLD  192   // padded vec row stride (bf16 elements)
#define SNP  24576 // padded sort-row length = 16*1536

typedef __attribute__((ext_vector_type(8))) short bf16x8;
typedef __attribute__((ext_vector_type(4))) float f32x4;

__device__ __forceinline__ ushort f2bf(float f) {
    unsigned u = __float_as_uint(f);
    u += 0x7FFFu + ((u >> 16) & 1u);
    return (ushort)(u >> 16);
}

// ---------------------------------------------------------------------------
// Kernel 0: convert Ws_out (181x190 fp32) -> Abf (192x192 bf16, zero-padded)
// ---------------------------------------------------------------------------
__global__ __launch_bounds__(256) void k_prep(
    const float* __restrict__ W, ushort* __restrict__ Abf)
{
    int i = blockIdx.x * 256 + threadIdx.x;   // grid 144*256 = 36864 exact
    int k = i / 192, d = i - k * 192;
    Abf[i] = (k < KK && d < DEMB) ? f2bf(W[k * DEMB + d]) : (ushort)0;
}

// ---------------------------------------------------------------------------
// Kernel 1: per-permutation inner embed -> vec (PP x VLD, bf16)
// Round-17: occupancy fix. wd row is loop-invariant per lane -> hoisted into
// 27 REGISTERS (one-time global load); WdS (21.5 KB) deleted -> LDS 6.1 KB.
// launch_bounds(256,6) + grid 1536 = 6 blocks/CU = 24 waves/CU (was 20
// nominal, 36% measured — kernel is latency-bound at real VALU ~38%).
// ONE sort array per lane (iron law: 2+ arrays spill — r8/r15). Pruned
// Batcher (b<30; INF pads at 30,31 immovable — verified r15).
// ---------------------------------------------------------------------------
__global__ __launch_bounds__(256, 6) void k_inner(
    const float* __restrict__ M,      // 3 x 30
    const float* __restrict__ Ws_in,  // 181 x 3
    const float* __restrict__ Wd_in,  // 181 x 27
    ushort* __restrict__ vec)         // PP x VLD (bf16)
{
    __shared__ float Gs[NPTS * 32];   // 3.84 KB
    __shared__ float WsS[192 * 3];    // 2.3 KB

    const int tid = threadIdx.x;

    for (int i = tid; i < 192 * 3; i += 256) WsS[i] = (i < KK * 3) ? Ws_in[i] : 0.f;
    for (int e = tid; e < NPTS * 32; e += 256) {
        int a = e >> 5, b = e & 31;
        Gs[e] = (b < NPTS)
            ? (M[a] * M[b] + M[NPTS + a] * M[NPTS + b] + M[2 * NPTS + a] * M[2 * NPTS + b])
            : 0.f;
    }
    __syncthreads();

    const int wave = tid >> 6;
    const int lane = tid & 63;
    const int wid = blockIdx.x * 4 + wave;    // 0..6143
    const int chunk = wid % 3;
    const int pstream = wid / 3;              // 0..2047
    const int k = chunk * 64 + lane;          // 0..191

    const float INF = __builtin_inff();
    const bool kvalid = (k < KK);
    const float w0 = WsS[k * 3 + 0];
    const float w1 = WsS[k * 3 + 1];
    const float w2 = WsS[k * 3 + 2];

    // loop-invariant Wd row -> registers (one-time, L2-hot)
    float wdr[27];
#pragma unroll
    for (int m = 0; m < 27; ++m)
        wdr[m] = kvalid ? Wd_in[k * 27 + m] : 0.f;

    for (int p = pstream; p < PP; p += 2048) {
        int i0 = p / 812;            // 812 = 29*28
        int r  = p - i0 * 812;
        int i1 = r / 28;
        int i2 = r - i1 * 28;
        int c0 = i0;
        int c1 = i1 + (i1 >= c0 ? 1 : 0);
        int lo = min(c0, c1), hi = max(c0, c1);
        int c2 = i2;
        if (c2 >= lo) c2++;
        if (c2 >= hi) c2++;

        ushort* vrow = vec + (long)p * VLD;

        if (chunk == 0 && lane < 9) {
            int i = lane / 3, j = lane % 3;
            int ci = (i == 0) ? c0 : ((i == 1) ? c1 : c2);
            int cj = (j == 0) ? c0 : ((j == 1) ? c1 : c2);
            vrow[lane] = f2bf(Gs[(ci << 5) + cj]);
        }

        const float* g0 = Gs + (c0 << 5);
        const float* g1 = Gs + (c1 << 5);
        const float* g2 = Gs + (c2 << 5);
        const unsigned xmask = (1u << c0) | (1u << c1) | (1u << c2);

        float v[30];
#pragma unroll
        for (int q = 0; q < 8; ++q) {
            float4 x0 = *(const float4*)&g0[q * 4];
            float4 x1 = *(const float4*)&g1[q * 4];
            float4 x2 = *(const float4*)&g2[q * 4];
            int j0 = q * 4;
            if (j0 + 0 < NPTS) { float val = w0 * x0.x + w1 * x1.x + w2 * x2.x;
                v[j0 + 0] = ((xmask >> (j0 + 0)) & 1u) ? INF : val; }
            if (j0 + 1 < NPTS) { float val = w0 * x0.y + w1 * x1.y + w2 * x2.y;
                v[j0 + 1] = ((xmask >> (j0 + 1)) & 1u) ? INF : val; }
            if (j0 + 2 < NPTS) { float val = w0 * x0.z + w1 * x1.z + w2 * x2.z;
                v[j0 + 2] = ((xmask >> (j0 + 2)) & 1u) ? INF : val; }
            if (j0 + 3 < NPTS) { float val = w0 * x0.w + w1 * x1.w + w2 * x2.w;
                v[j0 + 3] = ((xmask >> (j0 + 3)) & 1u) ? INF : val; }
        }

        // Pruned Batcher odd-even mergesort (n=32 network, CEs with b>=30
        // removed: slots 30,31 would hold immovable INF pads — verified r15)
#pragma unroll
        for (int pw = 1; pw < 32; pw <<= 1) {
#pragma unroll
            for (int kk = pw; kk >= 1; kk >>= 1) {
#pragma unroll
                for (int j = kk % pw; j + kk < 32; j += 2 * kk) {
#pragma unroll
                    for (int i = 0; i < kk; ++i) {
                        int a = i + j, b = i + j + kk;
                        if (b < NPTS && (a / (pw * 2) == b / (pw * 2))) {
                            float x = v[a], y = v[b];
                            v[a] = fminf(x, y);
                            v[b] = fmaxf(x, y);
                        }
                    }
                }
            }
        }

        if (kvalid) {
            float emb = 0.f;
#pragma unroll
            for (int m = 0; m < 27; ++m) emb += wdr[m] * v[m];
            vrow[9 + k] = f2bf(emb);
        } else if (k < 183) {
            vrow[9 + k] = 0;    // pad entries 190,191 stay zero
        }
    }
}

// ---------------------------------------------------------------------------
// Kernel 2: sm2T[k][p] via bf16 MFMA, no LDS [frozen, round 16]
// ---------------------------------------------------------------------------
__global__ __launch_bounds__(256) void k_gemm(
    const ushort* __restrict__ vecB,  // PP x 192 bf16
    const ushort* __restrict__ Abf,   // 192 x 192 bf16
    float* __restrict__ sm2T)         // 181 x PP fp32
{
    const int tid  = threadIdx.x;
    const int bid  = blockIdx.x;
    const int tile = bid >> 1;        // p-tile (64 p's)
    const int half = bid & 1;         // kt half: 0 -> kt 0..5, 1 -> kt 6..11
    const int wave = tid >> 6;
    const int lane = tid & 63;
    const int n = lane & 15;
    const int quad = lane >> 4;
    const int p = tile * 64 + wave * 16 + n;

    bf16x8 bfrag[6];
    if (p < PP) {
        const ushort* row = vecB + (long)p * VLD;
#pragma unroll
        for (int kc = 0; kc < 6; ++kc)
            bfrag[kc] = *(const bf16x8*)&row[kc * 32 + quad * 8];
    } else {
        bf16x8 z = {0, 0, 0, 0, 0, 0, 0, 0};
#pragma unroll
        for (int kc = 0; kc < 6; ++kc) bfrag[kc] = z;
    }

#pragma unroll
    for (int i = 0; i < 6; ++i) {
        const int kt = half * 6 + i;
        f32x4 acc = {0.f, 0.f, 0.f, 0.f};
        const ushort* arow = Abf + (kt * 16 + n) * 192;
#pragma unroll
        for (int kc = 0; kc < 6; ++kc) {
            bf16x8 afrag = *(const bf16x8*)&arow[kc * 32 + quad * 8];
            acc = __builtin_amdgcn_mfma_f32_16x16x32_bf16(afrag, bfrag[kc], acc, 0, 0, 0);
        }
        if (p < PP) {
            int k0 = kt * 16 + quad * 4;
#pragma unroll
            for (int r = 0; r < 4; ++r) {
                int kg = k0 + r;
                if (kg < KK) sm2T[(long)kg * PP + p] = acc[r];
            }
        }
    }
}

// ---------------------------------------------------------------------------
// Kernel 3: per-k LSD radix sort, high 24 bits, 3 passes [frozen, round 12]
// ---------------------------------------------------------------------------
#define WAVES  16
#define WCHUNK 1536

__device__ __forceinline__ unsigned long long matchany9(unsigned d) {
    unsigned long long m = ~0ull;
#pragma unroll
    for (int b = 0; b < 9; ++b) {
        unsigned bit = (d >> b) & 1u;
        unsigned long long bal = __ballot(bit);
        m &= bit ? bal : ~bal;
    }
    return m;
}

__device__ __forceinline__ unsigned long long matchany8(unsigned d) {
    unsigned long long m = ~0ull;
#pragma unroll
    for (int b = 0; b < 8; ++b) {
        unsigned bit = (d >> b) & 1u;
        unsigned long long bal = __ballot(bit);
        m &= bit ? bal : ~bal;
    }
    return m;
}

__device__ __forceinline__ void scan_hist(unsigned* cntC, unsigned* cntZ,
                                          unsigned* tot, int tid) {
    if (tid < 256) {
        unsigned run = 0;
        for (int w = 0; w < WAVES; ++w) {
            unsigned t = cntC[w * 256 + tid];
            cntC[w * 256 + tid] = run;
            run += t;
        }
        tot[tid] = run;
    }
    __syncthreads();
    if (tid < 64) {
        unsigned t0 = tot[tid * 4], t1 = tot[tid * 4 + 1];
        unsigned t2 = tot[tid * 4 + 2], t3 = tot[tid * 4 + 3];
        unsigned s = t0 + t1 + t2 + t3;
        unsigned sc = s;
#pragma unroll
        for (int off = 1; off < 64; off <<= 1) {
            unsigned o = (unsigned)__shfl_up((int)sc, off, 64);
            if (tid >= off) sc += o;
        }
        unsigned ex = sc - s;
        tot[tid * 4]     = ex + t0;
        tot[tid * 4 + 1] = ex + t0 + t1;
        tot[tid * 4 + 2] = ex + t0 + t1 + t2;
        tot[tid * 4 + 3] = ex + s;
    } else if (cntZ) {
        for (int i = tid - 64; i < WAVES * 256; i += 1024 - 64) cntZ[i] = 0;
    }
    __syncthreads();
    for (int i = tid; i < WAVES * 256; i += 1024) {
        int d = i & 255;
        unsigned db = (d == 0) ? 0u : tot[d - 1];
        cntC[i] += db;
    }
    __syncthreads();
}

__global__ __launch_bounds__(1024) void k_sort(
    float* sm2T,
    unsigned* bufA,           // 181 x SNP scratch
    const float* __restrict__ WdOut,
    float* __restrict__ out)
{
    __shared__ unsigned keysL[SNP];
    __shared__ unsigned cntA[WAVES * 256];
    __shared__ unsigned cntB[WAVES * 256];
    __shared__ unsigned tot[256];
    __shared__ float red[WAVES];

    const int tid  = threadIdx.x;
    const int wave = tid >> 6;
    const int lane = tid & 63;
    const int k    = blockIdx.x;

    const unsigned* rowU = (const unsigned*)sm2T + (long)k * PP;
    unsigned* bA         = bufA + (long)k * SNP;
    const float* wrow    = WdOut + (long)k * PP;

    const int base_idx = wave * WCHUNK + lane;
    const int wbase = wave * 256;
    const unsigned long long lt_mask = (1ull << lane) - 1ull;

    for (int i = tid; i < WAVES * 256; i += 1024) cntA[i] = 0;
    for (int i = PP + tid; i < SNP; i += 1024) keysL[i] = 0xFFFFFFFFu;
    __syncthreads();

    for (int j = 0; j < 24; ++j) {
        int idx = base_idx + j * 64;
        if (idx < PP) {
            unsigned u = rowU[idx];
            u = (u & 0x80000000u) ? ~u : (u | 0x80000000u);
            atomicAdd(&cntA[wbase + ((u >> 8) & 255u)], 1u);
        }
    }
    __syncthreads();
    scan_hist(cntA, cntB, tot, tid);

    for (int j = 0; j < 24; ++j) {
        int idx = base_idx + j * 64;
        bool valid = (idx < PP);
        unsigned u = 0u;
        if (valid) {
            u = rowU[idx];
            u = (u & 0x80000000u) ? ~u : (u | 0x80000000u);
        }
        unsigned d9 = ((u >> 8) & 255u) | (valid ? 0u : 256u);
        unsigned long long mm = matchany9(d9);
        if (valid) {
            int leader = __ffsll(mm) - 1;
            unsigned myrank = (unsigned)__popcll(mm & lt_mask);
            unsigned old = 0;
            if (lane == leader)
                old = atomicAdd(&cntA[wbase + (d9 & 255u)], (unsigned)__popcll(mm));
            old = (unsigned)__shfl((int)old, leader, 64);
            unsigned dest = old + myrank;
            keysL[dest] = u;
            atomicAdd(&cntB[(dest / WCHUNK) * 256 + ((u >> 16) & 255u)], 1u);
        }
    }
    __syncthreads();
    if (tid == 0) cntB[15 * 256 + 255] += (SNP - PP);
    __syncthreads();
    scan_hist(cntB, cntA, tot, tid);

    for (int j = 0; j < 24; ++j) {
        int idx = base_idx + j * 64;
        unsigned u = keysL[idx];
        unsigned d = (u >> 16) & 255u;
        unsigned long long mm = matchany8(d);
        int leader = __ffsll(mm) - 1;
        unsigned myrank = (unsigned)__popcll(mm & lt_mask);
        unsigned old = 0;
        if (lane == leader)
            old = atomicAdd(&cntB[wbase + d], (unsigned)__popcll(mm));
        old = (unsigned)__shfl((int)old, leader, 64);
        unsigned dest = old + myrank;
        bA[dest] = u;
        atomicAdd(&cntA[(dest / WCHUNK) * 256 + ((u >> 24) & 255u)], 1u);
    }
    __syncthreads();
    scan_hist(cntA, (unsigned*)0, tot, tid);

    float local = 0.f;
    for (int j = 0; j < 24; ++j) {
        int idx = base_idx + j * 64;
        unsigned u = bA[idx];
        unsigned d = (u >> 24) & 255u;
        unsigned long long mm = matchany8(d);
        int leader = __ffsll(mm) - 1;
        unsigned myrank = (unsigned)__popcll(mm & lt_mask);
        unsigned old = 0;
        if (lane == leader)
            old = atomicAdd(&cntA[wbase + d], (unsigned)__popcll(mm));
        old = (unsigned)__shfl((int)old, leader, 64);
        unsigned dest = old + myrank;
        if (dest < PP) {
            unsigned raw = (u & 0x80000000u) ? (u & 0x7FFFFFFFu) : ~u;
            local += wrow[dest] * __uint_as_float(raw);
        }
    }

#pragma unroll
    for (int off = 32; off > 0; off >>= 1)
        local += __shfl_down(local, off, 64);
    if (lane == 0) red[wave] = local;
    __syncthreads();
    if (tid < WAVES) {
        float x = red[tid];
#pragma unroll
        for (int off = 8; off > 0; off >>= 1)
            x += __shfl_down(x, off, 64);
        if (tid == 0) out[k] = x;
    }
}

// ---------------------------------------------------------------------------
extern "C" void kernel_launch(void* const* d_in, const int* in_sizes, int n_in,
                              void* d_out, int out_size, void* d_ws, size_t ws_size,
                              hipStream_t stream) {
    const float* M      = (const float*)d_in[0];
    const float* Ws_in  = (const float*)d_in[1];
    const float* Wd_in  = (const float*)d_in[2];
    const float* Ws_out = (const float*)d_in[3];
    const float* Wd_out = (const float*)d_in[4];
    float* out = (float*)d_out;

    // workspace layout (35.5 MB):
    // [0, 17.79 MB):  bufA (181 x SNP u32); vecB (PP x 192 bf16) overlays head
    // [17.79, 35.43): sm2T (181 x PP fp32)
    // [35.43, +74KB): Abf (192 x 192 bf16)
    char* ws = (char*)d_ws;
    ushort*   vecB = (ushort*)ws;
    unsigned* bufA = (unsigned*)ws;
    float*    sm2T = (float*)(ws + (size_t)KK * SNP * 4);
    ushort*   Abf  = (ushort*)(ws + (size_t)KK * SNP * 4 + (size_t)KK * PP * 4);

    k_prep<<<144, 256, 0, stream>>>(Ws_out, Abf);

    k_inner<<<1536, 256, 0, stream>>>(M, Ws_in, Wd_in, vecB);

    k_gemm<<<((PP + 63) / 64) * 2, 256, 0, stream>>>(vecB, Abf, sm2T);

    k_sort<<<KK, 1024, 0, stream>>>(sm2T, bufA, Wd_out, out);
}

// Round 18
// 255.828 us; speedup vs baseline: 1.0172x; 1.0172x over previous
//
#include <hip/hip_runtime.h>
#include <hip/hip_bf16.h>

#define DIMK 3
#define NPTS 30
#define KK   181
#define PP   24360
#define DEMB 190
#define VLD  192   // padded vec row stride (bf16 elements)
#define SNP  24576 // padded row length = 16*1536 (sort rows AND sm2T stride)

typedef __attribute__((ext_vector_type(8))) short bf16x8;
typedef __attribute__((ext_vector_type(4))) float f32x4;

__device__ __forceinline__ ushort f2bf(float f) {
    unsigned u = __float_as_uint(f);
    u += 0x7FFFu + ((u >> 16) & 1u);
    return (ushort)(u >> 16);
}

__device__ __forceinline__ unsigned enc_key(float f) {
    unsigned u = __float_as_uint(f);
    return (u & 0x80000000u) ? ~u : (u | 0x80000000u);
}

// ---------------------------------------------------------------------------
// Kernel 1: per-permutation inner embed -> vec (PP x VLD, bf16)
// [r14/r16 proven version — ONE sort array per lane (iron law: any second
// per-lane array, even loop-invariant, is demoted to scratch — r8/r15/r17).]
// k_prep folded into the preamble: converts Ws_out -> Abf (192x192 bf16).
// ---------------------------------------------------------------------------
__global__ __launch_bounds__(256, 5) void k_inner(
    const float* __restrict__ M,      // 3 x 30
    const float* __restrict__ Ws_in,  // 181 x 3
    const float* __restrict__ Wd_in,  // 181 x 27
    const float* __restrict__ Wout,   // 181 x 190
    ushort* __restrict__ Abf,         // 192 x 192 bf16 out
    ushort* __restrict__ vec)         // PP x VLD (bf16)
{
    __shared__ float Gs[NPTS * 32];
    __shared__ float WsS[192 * 3];
    __shared__ float WdS[192 * 28];

    const int tid = threadIdx.x;

    // folded k_prep: one element per thread for the first 144 blocks
    {
        int gid = blockIdx.x * 256 + tid;
        if (gid < 192 * 192) {
            int k = gid / 192, d = gid - k * 192;
            Abf[gid] = (k < KK && d < DEMB) ? f2bf(Wout[k * DEMB + d]) : (ushort)0;
        }
    }

    for (int i = tid; i < 192 * 3; i += 256) WsS[i] = (i < KK * 3) ? Ws_in[i] : 0.f;
    for (int i = tid; i < 192 * 28; i += 256) {
        int k = i / 28, m = i - k * 28;
        WdS[i] = (k < KK && m < 27) ? Wd_in[k * 27 + m] : 0.f;
    }
    for (int e = tid; e < NPTS * 32; e += 256) {
        int a = e >> 5, b = e & 31;
        Gs[e] = (b < NPTS)
            ? (M[a] * M[b] + M[NPTS + a] * M[NPTS + b] + M[2 * NPTS + a] * M[2 * NPTS + b])
            : 0.f;
    }
    __syncthreads();

    const int wave = tid >> 6;
    const int lane = tid & 63;
    const int wid = blockIdx.x * 4 + wave;
    const int chunk = wid % 3;
    const int pstream = wid / 3;
    const int nstream = (chunk == 2) ? 1706 : 1707;
    const int k = chunk * 64 + lane;

    const float INF = __builtin_inff();
    const bool kvalid = (k < KK);
    const float w0 = WsS[k * 3 + 0];
    const float w1 = WsS[k * 3 + 1];
    const float w2 = WsS[k * 3 + 2];
    const float* wd = WdS + k * 28;

    for (int p = pstream; p < PP; p += nstream) {
        int i0 = p / 812;            // 812 = 29*28
        int r  = p - i0 * 812;
        int i1 = r / 28;
        int i2 = r - i1 * 28;
        int c0 = i0;
        int c1 = i1 + (i1 >= c0 ? 1 : 0);
        int lo = min(c0, c1), hi = max(c0, c1);
        int c2 = i2;
        if (c2 >= lo) c2++;
        if (c2 >= hi) c2++;

        ushort* vrow = vec + (long)p * VLD;

        if (chunk == 0 && lane < 9) {
            int i = lane / 3, j = lane % 3;
            int ci = (i == 0) ? c0 : ((i == 1) ? c1 : c2);
            int cj = (j == 0) ? c0 : ((j == 1) ? c1 : c2);
            vrow[lane] = f2bf(Gs[(ci << 5) + cj]);
        }

        const float* g0 = Gs + (c0 << 5);
        const float* g1 = Gs + (c1 << 5);
        const float* g2 = Gs + (c2 << 5);
        const unsigned xmask = (1u << c0) | (1u << c1) | (1u << c2);

        float v[32];
#pragma unroll
        for (int q = 0; q < 8; ++q) {
            float4 x0 = *(const float4*)&g0[q * 4];
            float4 x1 = *(const float4*)&g1[q * 4];
            float4 x2 = *(const float4*)&g2[q * 4];
            int j0 = q * 4;
            if (j0 + 0 < NPTS) { float val = w0 * x0.x + w1 * x1.x + w2 * x2.x;
                v[j0 + 0] = ((xmask >> (j0 + 0)) & 1u) ? INF : val; }
            if (j0 + 1 < NPTS) { float val = w0 * x0.y + w1 * x1.y + w2 * x2.y;
                v[j0 + 1] = ((xmask >> (j0 + 1)) & 1u) ? INF : val; }
            if (j0 + 2 < NPTS) { float val = w0 * x0.z + w1 * x1.z + w2 * x2.z;
                v[j0 + 2] = ((xmask >> (j0 + 2)) & 1u) ? INF : val; }
            if (j0 + 3 < NPTS) { float val = w0 * x0.w + w1 * x1.w + w2 * x2.w;
                v[j0 + 3] = ((xmask >> (j0 + 3)) & 1u) ? INF : val; }
        }
        v[30] = INF;
        v[31] = INF;

        // Batcher odd-even mergesort, n=32, ascending
#pragma unroll
        for (int pw = 1; pw < 32; pw <<= 1) {
#pragma unroll
            for (int kk = pw; kk >= 1; kk >>= 1) {
#pragma unroll
                for (int j = kk % pw; j + kk < 32; j += 2 * kk) {
#pragma unroll
                    for (int i = 0; i < kk; ++i) {
                        int a = i + j, b = i + j + kk;
                        if (a / (pw * 2) == b / (pw * 2)) {
                            float x = v[a], y = v[b];
                            v[a] = fminf(x, y);
                            v[b] = fmaxf(x, y);
                        }
                    }
                }
            }
        }

        if (kvalid) {
            v[27] = 0.f;
            float emb = 0.f;
#pragma unroll
            for (int q = 0; q < 7; ++q) {
                float4 w4 = *(const float4*)&wd[q * 4];
                emb += w4.x * v[q * 4] + w4.y * v[q * 4 + 1]
                     + w4.z * v[q * 4 + 2] + w4.w * v[q * 4 + 3];
            }
            vrow[9 + k] = f2bf(emb);
        } else if (k < 183) {
            vrow[9 + k] = 0;    // pad entries 190,191 stay zero
        }
    }
}

// ---------------------------------------------------------------------------
// Kernel 2: sm2TP[k][p] via bf16 MFMA, no LDS [r16 base].
// Round-18: rows have SNP stride; stores are pre-ENCODED sort keys; lanes
// with p in [PP,SNP) store 0xFFFFFFFF pads (encoded max-finite = 0xFF7FFFFF
// < 0xFFFFFFFF, so pads provably sort last and land at dest >= PP).
// Grid covers 24576 p's = 384 tiles x 2 kt-halves.
// ---------------------------------------------------------------------------
__global__ __launch_bounds__(256) void k_gemm(
    const ushort* __restrict__ vecB,  // PP x 192 bf16
    const ushort* __restrict__ Abf,   // 192 x 192 bf16
    unsigned* __restrict__ sm2TP)     // 181 x SNP encoded keys
{
    const int tid  = threadIdx.x;
    const int bid  = blockIdx.x;
    const int tile = bid >> 1;        // p-tile (64 p's)
    const int half = bid & 1;         // kt half: 0 -> kt 0..5, 1 -> kt 6..11
    const int wave = tid >> 6;
    const int lane = tid & 63;
    const int n = lane & 15;
    const int quad = lane >> 4;
    const int p = tile * 64 + wave * 16 + n;   // < SNP by grid construction

    bf16x8 bfrag[6];
    if (p < PP) {
        const ushort* row = vecB + (long)p * VLD;
#pragma unroll
        for (int kc = 0; kc < 6; ++kc)
            bfrag[kc] = *(const bf16x8*)&row[kc * 32 + quad * 8];
    } else {
        bf16x8 z = {0, 0, 0, 0, 0, 0, 0, 0};
#pragma unroll
        for (int kc = 0; kc < 6; ++kc) bfrag[kc] = z;
    }

#pragma unroll
    for (int i = 0; i < 6; ++i) {
        const int kt = half * 6 + i;
        f32x4 acc = {0.f, 0.f, 0.f, 0.f};
        const ushort* arow = Abf + (kt * 16 + n) * 192;
#pragma unroll
        for (int kc = 0; kc < 6; ++kc) {
            bf16x8 afrag = *(const bf16x8*)&arow[kc * 32 + quad * 8];
            acc = __builtin_amdgcn_mfma_f32_16x16x32_bf16(afrag, bfrag[kc], acc, 0, 0, 0);
        }
        int k0 = kt * 16 + quad * 4;
#pragma unroll
        for (int r = 0; r < 4; ++r) {
            int kg = k0 + r;
            if (kg < KK)
                sm2TP[(long)kg * SNP + p] = (p < PP) ? enc_key(acc[r]) : 0xFFFFFFFFu;
        }
    }
}

// ---------------------------------------------------------------------------
// Kernel 3: per-k LSD radix sort, high 24 bits, 3 passes. Round-18: fully
// uniform — source rows are pre-encoded and pre-padded to SNP, so every
// traversal is branch-free (matchany8 everywhere, no validity guards, no
// pad-count hack). Fused next-pass histograms + fused final dot.
// ---------------------------------------------------------------------------
#define WAVES  16
#define WCHUNK 1536

__device__ __forceinline__ unsigned long long matchany8(unsigned d) {
    unsigned long long m = ~0ull;
#pragma unroll
    for (int b = 0; b < 8; ++b) {
        unsigned bit = (d >> b) & 1u;
        unsigned long long bal = __ballot(bit);
        m &= bit ? bal : ~bal;
    }
    return m;
}

__device__ __forceinline__ void scan_hist(unsigned* cntC, unsigned* cntZ,
                                          unsigned* tot, int tid) {
    if (tid < 256) {
        unsigned run = 0;
        for (int w = 0; w < WAVES; ++w) {
            unsigned t = cntC[w * 256 + tid];
            cntC[w * 256 + tid] = run;
            run += t;
        }
        tot[tid] = run;
    }
    __syncthreads();
    if (tid < 64) {
        unsigned t0 = tot[tid * 4], t1 = tot[tid * 4 + 1];
        unsigned t2 = tot[tid * 4 + 2], t3 = tot[tid * 4 + 3];
        unsigned s = t0 + t1 + t2 + t3;
        unsigned sc = s;
#pragma unroll
        for (int off = 1; off < 64; off <<= 1) {
            unsigned o = (unsigned)__shfl_up((int)sc, off, 64);
            if (tid >= off) sc += o;
        }
        unsigned ex = sc - s;
        tot[tid * 4]     = ex + t0;
        tot[tid * 4 + 1] = ex + t0 + t1;
        tot[tid * 4 + 2] = ex + t0 + t1 + t2;
        tot[tid * 4 + 3] = ex + s;
    } else if (cntZ) {
        for (int i = tid - 64; i < WAVES * 256; i += 1024 - 64) cntZ[i] = 0;
    }
    __syncthreads();
    for (int i = tid; i < WAVES * 256; i += 1024) {
        int d = i & 255;
        unsigned db = (d == 0) ? 0u : tot[d - 1];
        cntC[i] += db;
    }
    __syncthreads();
}

__global__ __launch_bounds__(1024) void k_sort(
    const unsigned* __restrict__ sm2TP,  // 181 x SNP encoded keys (padded)
    unsigned* bufA,                      // 181 x SNP scratch
    const float* __restrict__ WdOut,     // 181 x PP
    float* __restrict__ out)             // 181
{
    __shared__ unsigned keysL[SNP];
    __shared__ unsigned cntA[WAVES * 256];
    __shared__ unsigned cntB[WAVES * 256];
    __shared__ unsigned tot[256];
    __shared__ float red[WAVES];

    const int tid  = threadIdx.x;
    const int wave = tid >> 6;
    const int lane = tid & 63;
    const int k    = blockIdx.x;

    const unsigned* rowU = sm2TP + (long)k * SNP;
    unsigned* bA         = bufA + (long)k * SNP;
    const float* wrow    = WdOut + (long)k * PP;

    const int base_idx = wave * WCHUNK + lane;
    const int wbase = wave * 256;
    const unsigned long long lt_mask = (1ull << lane) - 1ull;

    for (int i = tid; i < WAVES * 256; i += 1024) cntA[i] = 0;
    __syncthreads();

    // ---- count0: bits 8-15, uniform over SNP ----
    for (int j = 0; j < 24; ++j) {
        unsigned u = rowU[base_idx + j * 64];
        atomicAdd(&cntA[wbase + ((u >> 8) & 255u)], 1u);
    }
    __syncthreads();
    scan_hist(cntA, cntB, tot, tid);   // also zeroes cntB

    // ---- scatter0: G -> LDS on bits 8-15, fused count1 (bits 16-23) ----
    for (int j = 0; j < 24; ++j) {
        unsigned u = rowU[base_idx + j * 64];
        unsigned d = (u >> 8) & 255u;
        unsigned long long mm = matchany8(d);
        int leader = __ffsll(mm) - 1;
        unsigned myrank = (unsigned)__popcll(mm & lt_mask);
        unsigned old = 0;
        if (lane == leader)
            old = atomicAdd(&cntA[wbase + d], (unsigned)__popcll(mm));
        old = (unsigned)__shfl((int)old, leader, 64);
        unsigned dest = old + myrank;
        keysL[dest] = u;
        atomicAdd(&cntB[(dest / WCHUNK) * 256 + ((u >> 16) & 255u)], 1u);
    }
    __syncthreads();
    scan_hist(cntB, cntA, tot, tid);   // zeroes cntA

    // ---- scatter1: LDS -> G on bits 16-23, fused count2 (bits 24-31) ----
    for (int j = 0; j < 24; ++j) {
        unsigned u = keysL[base_idx + j * 64];
        unsigned d = (u >> 16) & 255u;
        unsigned long long mm = matchany8(d);
        int leader = __ffsll(mm) - 1;
        unsigned myrank = (unsigned)__popcll(mm & lt_mask);
        unsigned old = 0;
        if (lane == leader)
            old = atomicAdd(&cntB[wbase + d], (unsigned)__popcll(mm));
        old = (unsigned)__shfl((int)old, leader, 64);
        unsigned dest = old + myrank;
        bA[dest] = u;
        atomicAdd(&cntA[(dest / WCHUNK) * 256 + ((u >> 24) & 255u)], 1u);
    }
    __syncthreads();
    scan_hist(cntA, (unsigned*)0, tot, tid);

    // ---- scatter2: G -> fused dot on bits 24-31 (pads land at dest>=PP) ----
    float local = 0.f;
    for (int j = 0; j < 24; ++j) {
        unsigned u = bA[base_idx + j * 64];
        unsigned d = (u >> 24) & 255u;
        unsigned long long mm = matchany8(d);
        int leader = __ffsll(mm) - 1;
        unsigned myrank = (unsigned)__popcll(mm & lt_mask);
        unsigned old = 0;
        if (lane == leader)
            old = atomicAdd(&cntA[wbase + d], (unsigned)__popcll(mm));
        old = (unsigned)__shfl((int)old, leader, 64);
        unsigned dest = old + myrank;
        if (dest < PP) {
            unsigned raw = (u & 0x80000000u) ? (u & 0x7FFFFFFFu) : ~u;
            local += wrow[dest] * __uint_as_float(raw);
        }
    }

#pragma unroll
    for (int off = 32; off > 0; off >>= 1)
        local += __shfl_down(local, off, 64);
    if (lane == 0) red[wave] = local;
    __syncthreads();
    if (tid < WAVES) {
        float x = red[tid];
#pragma unroll
        for (int off = 8; off > 0; off >>= 1)
            x += __shfl_down(x, off, 64);
        if (tid == 0) out[k] = x;
    }
}

// ---------------------------------------------------------------------------
extern "C" void kernel_launch(void* const* d_in, const int* in_sizes, int n_in,
                              void* d_out, int out_size, void* d_ws, size_t ws_size,
                              hipStream_t stream) {
    const float* M      = (const float*)d_in[0];
    const float* Ws_in  = (const float*)d_in[1];
    const float* Wd_in  = (const float*)d_in[2];
    const float* Ws_out = (const float*)d_in[3];
    const float* Wd_out = (const float*)d_in[4];
    float* out = (float*)d_out;

    // workspace layout (35.73 MB < 36.35 MB proven in rounds 1-13):
    // [0, 17.79 MB):   bufA (181 x SNP u32); vecB (PP x 192 bf16) overlays head
    // [17.79, 35.59):  sm2TP (181 x SNP u32, encoded keys)
    // [35.59, +147KB): Abf (192 x 192 bf16)
    char* ws = (char*)d_ws;
    ushort*   vecB  = (ushort*)ws;
    unsigned* bufA  = (unsigned*)ws;
    unsigned* sm2TP = (unsigned*)(ws + (size_t)KK * SNP * 4);
    ushort*   Abf   = (ushort*)(ws + 2 * (size_t)KK * SNP * 4);

    k_inner<<<1280, 256, 0, stream>>>(M, Ws_in, Wd_in, Ws_out, Abf, vecB);

    k_gemm<<<(SNP / 64) * 2, 256, 0, stream>>>(vecB, Abf, sm2TP);

    k_sort<<<KK, 1024, 0, stream>>>(sm2TP, bufA, Wd_out, out);
}

// Round 19
// 225.885 us; speedup vs baseline: 1.1520x; 1.1326x over previous
//
#include <hip/hip_runtime.h>
#include <hip/hip_bf16.h>

#define DIMK 3
#define NPTS 30
#define KK   181
#define PP   24360
#define DEMB 190
#define VLD  192   // padded vec row stride (bf16 elements)
#define SNP  24576 // padded row length = 16*1536 (sort rows AND sm2T stride)

typedef __attribute__((ext_vector_type(8))) short bf16x8;
typedef __attribute__((ext_vector_type(4))) float f32x4;

__device__ __forceinline__ ushort f2bf(float f) {
    unsigned u = __float_as_uint(f);
    u += 0x7FFFu + ((u >> 16) & 1u);
    return (ushort)(u >> 16);
}

// ---------------------------------------------------------------------------
// Kernel 1: per-permutation inner embed -> vec (PP x VLD, bf16)
// [byte-frozen r14/r16/r18 — ONE sort array per lane (iron law); k_prep
// folded into preamble]
// ---------------------------------------------------------------------------
__global__ __launch_bounds__(256, 5) void k_inner(
    const float* __restrict__ M,      // 3 x 30
    const float* __restrict__ Ws_in,  // 181 x 3
    const float* __restrict__ Wd_in,  // 181 x 27
    const float* __restrict__ Wout,   // 181 x 190
    ushort* __restrict__ Abf,         // 192 x 192 bf16 out
    ushort* __restrict__ vec)         // PP x VLD (bf16)
{
    __shared__ float Gs[NPTS * 32];
    __shared__ float WsS[192 * 3];
    __shared__ float WdS[192 * 28];

    const int tid = threadIdx.x;

    {
        int gid = blockIdx.x * 256 + tid;
        if (gid < 192 * 192) {
            int k = gid / 192, d = gid - k * 192;
            Abf[gid] = (k < KK && d < DEMB) ? f2bf(Wout[k * DEMB + d]) : (ushort)0;
        }
    }

    for (int i = tid; i < 192 * 3; i += 256) WsS[i] = (i < KK * 3) ? Ws_in[i] : 0.f;
    for (int i = tid; i < 192 * 28; i += 256) {
        int k = i / 28, m = i - k * 28;
        WdS[i] = (k < KK && m < 27) ? Wd_in[k * 27 + m] : 0.f;
    }
    for (int e = tid; e < NPTS * 32; e += 256) {
        int a = e >> 5, b = e & 31;
        Gs[e] = (b < NPTS)
            ? (M[a] * M[b] + M[NPTS + a] * M[NPTS + b] + M[2 * NPTS + a] * M[2 * NPTS + b])
            : 0.f;
    }
    __syncthreads();

    const int wave = tid >> 6;
    const int lane = tid & 63;
    const int wid = blockIdx.x * 4 + wave;
    const int chunk = wid % 3;
    const int pstream = wid / 3;
    const int nstream = (chunk == 2) ? 1706 : 1707;
    const int k = chunk * 64 + lane;

    const float INF = __builtin_inff();
    const bool kvalid = (k < KK);
    const float w0 = WsS[k * 3 + 0];
    const float w1 = WsS[k * 3 + 1];
    const float w2 = WsS[k * 3 + 2];
    const float* wd = WdS + k * 28;

    for (int p = pstream; p < PP; p += nstream) {
        int i0 = p / 812;            // 812 = 29*28
        int r  = p - i0 * 812;
        int i1 = r / 28;
        int i2 = r - i1 * 28;
        int c0 = i0;
        int c1 = i1 + (i1 >= c0 ? 1 : 0);
        int lo = min(c0, c1), hi = max(c0, c1);
        int c2 = i2;
        if (c2 >= lo) c2++;
        if (c2 >= hi) c2++;

        ushort* vrow = vec + (long)p * VLD;

        if (chunk == 0 && lane < 9) {
            int i = lane / 3, j = lane % 3;
            int ci = (i == 0) ? c0 : ((i == 1) ? c1 : c2);
            int cj = (j == 0) ? c0 : ((j == 1) ? c1 : c2);
            vrow[lane] = f2bf(Gs[(ci << 5) + cj]);
        }

        const float* g0 = Gs + (c0 << 5);
        const float* g1 = Gs + (c1 << 5);
        const float* g2 = Gs + (c2 << 5);
        const unsigned xmask = (1u << c0) | (1u << c1) | (1u << c2);

        float v[32];
#pragma unroll
        for (int q = 0; q < 8; ++q) {
            float4 x0 = *(const float4*)&g0[q * 4];
            float4 x1 = *(const float4*)&g1[q * 4];
            float4 x2 = *(const float4*)&g2[q * 4];
            int j0 = q * 4;
            if (j0 + 0 < NPTS) { float val = w0 * x0.x + w1 * x1.x + w2 * x2.x;
                v[j0 + 0] = ((xmask >> (j0 + 0)) & 1u) ? INF : val; }
            if (j0 + 1 < NPTS) { float val = w0 * x0.y + w1 * x1.y + w2 * x2.y;
                v[j0 + 1] = ((xmask >> (j0 + 1)) & 1u) ? INF : val; }
            if (j0 + 2 < NPTS) { float val = w0 * x0.z + w1 * x1.z + w2 * x2.z;
                v[j0 + 2] = ((xmask >> (j0 + 2)) & 1u) ? INF : val; }
            if (j0 + 3 < NPTS) { float val = w0 * x0.w + w1 * x1.w + w2 * x2.w;
                v[j0 + 3] = ((xmask >> (j0 + 3)) & 1u) ? INF : val; }
        }
        v[30] = INF;
        v[31] = INF;

        // Batcher odd-even mergesort, n=32, ascending
#pragma unroll
        for (int pw = 1; pw < 32; pw <<= 1) {
#pragma unroll
            for (int kk = pw; kk >= 1; kk >>= 1) {
#pragma unroll
                for (int j = kk % pw; j + kk < 32; j += 2 * kk) {
#pragma unroll
                    for (int i = 0; i < kk; ++i) {
                        int a = i + j, b = i + j + kk;
                        if (a / (pw * 2) == b / (pw * 2)) {
                            float x = v[a], y = v[b];
                            v[a] = fminf(x, y);
                            v[b] = fmaxf(x, y);
                        }
                    }
                }
            }
        }

        if (kvalid) {
            v[27] = 0.f;
            float emb = 0.f;
#pragma unroll
            for (int q = 0; q < 7; ++q) {
                float4 w4 = *(const float4*)&wd[q * 4];
                emb += w4.x * v[q * 4] + w4.y * v[q * 4 + 1]
                     + w4.z * v[q * 4 + 2] + w4.w * v[q * 4 + 3];
            }
            vrow[9 + k] = f2bf(emb);
        } else if (k < 183) {
            vrow[9 + k] = 0;
        }
    }
}

// ---------------------------------------------------------------------------
// Kernel 2: sm2TP[k][p] via bf16 MFMA, no LDS [r16 base].
// Round-19: stores 16-BIT encoded keys (RTN: (enc32+0x8000)>>16). Max finite
// key = 0xFF80 < 0xFFFF pad, so pads (p in [PP,SNP)) still sort last.
// ---------------------------------------------------------------------------
__global__ __launch_bounds__(256) void k_gemm(
    const ushort* __restrict__ vecB,  // PP x 192 bf16
    const ushort* __restrict__ Abf,   // 192 x 192 bf16
    ushort* __restrict__ sm2TP)       // 181 x SNP u16 encoded keys
{
    const int tid  = threadIdx.x;
    const int bid  = blockIdx.x;
    const int tile = bid >> 1;        // p-tile (64 p's)
    const int half = bid & 1;         // kt half
    const int wave = tid >> 6;
    const int lane = tid & 63;
    const int n = lane & 15;
    const int quad = lane >> 4;
    const int p = tile * 64 + wave * 16 + n;   // < SNP by grid construction

    bf16x8 bfrag[6];
    if (p < PP) {
        const ushort* row = vecB + (long)p * VLD;
#pragma unroll
        for (int kc = 0; kc < 6; ++kc)
            bfrag[kc] = *(const bf16x8*)&row[kc * 32 + quad * 8];
    } else {
        bf16x8 z = {0, 0, 0, 0, 0, 0, 0, 0};
#pragma unroll
        for (int kc = 0; kc < 6; ++kc) bfrag[kc] = z;
    }

#pragma unroll
    for (int i = 0; i < 6; ++i) {
        const int kt = half * 6 + i;
        f32x4 acc = {0.f, 0.f, 0.f, 0.f};
        const ushort* arow = Abf + (kt * 16 + n) * 192;
#pragma unroll
        for (int kc = 0; kc < 6; ++kc) {
            bf16x8 afrag = *(const bf16x8*)&arow[kc * 32 + quad * 8];
            acc = __builtin_amdgcn_mfma_f32_16x16x32_bf16(afrag, bfrag[kc], acc, 0, 0, 0);
        }
        int k0 = kt * 16 + quad * 4;
#pragma unroll
        for (int r = 0; r < 4; ++r) {
            int kg = k0 + r;
            if (kg < KK) {
                unsigned e;
                if (p < PP) {
                    unsigned u = __float_as_uint(acc[r]);
                    u = (u & 0x80000000u) ? ~u : (u | 0x80000000u);
                    e = (u + 0x8000u) >> 16;     // RTN 16-bit monotone key
                } else {
                    e = 0xFFFFu;                 // pad sorts strictly last
                }
                sm2TP[(long)kg * SNP + p] = (ushort)e;
            }
        }
    }
}

// ---------------------------------------------------------------------------
// Kernel 3: per-k radix sort on 16-BIT keys, 2 x 8-bit passes, 3 traversals,
// NO global intermediate (pass-0 scatter lands in 48 KB LDS; pass-1 scatter
// is the fused dot). Keys pre-encoded + pre-padded by k_gemm -> fully
// uniform, branch-free matchany8 everywhere. Dot value = bf16 reconstruction
// of the key (<= 1 bf16 ulp; inputs were bf16 anyway).
// ---------------------------------------------------------------------------
#define WAVES  16
#define WCHUNK 1536

__device__ __forceinline__ unsigned long long matchany8(unsigned d) {
    unsigned long long m = ~0ull;
#pragma unroll
    for (int b = 0; b < 8; ++b) {
        unsigned bit = (d >> b) & 1u;
        unsigned long long bal = __ballot(bit);
        m &= bit ? bal : ~bal;
    }
    return m;
}

__device__ __forceinline__ void scan_hist(unsigned* cntC, unsigned* cntZ,
                                          unsigned* tot, int tid) {
    if (tid < 256) {
        unsigned run = 0;
        for (int w = 0; w < WAVES; ++w) {
            unsigned t = cntC[w * 256 + tid];
            cntC[w * 256 + tid] = run;
            run += t;
        }
        tot[tid] = run;
    }
    __syncthreads();
    if (tid < 64) {
        unsigned t0 = tot[tid * 4], t1 = tot[tid * 4 + 1];
        unsigned t2 = tot[tid * 4 + 2], t3 = tot[tid * 4 + 3];
        unsigned s = t0 + t1 + t2 + t3;
        unsigned sc = s;
#pragma unroll
        for (int off = 1; off < 64; off <<= 1) {
            unsigned o = (unsigned)__shfl_up((int)sc, off, 64);
            if (tid >= off) sc += o;
        }
        unsigned ex = sc - s;
        tot[tid * 4]     = ex + t0;
        tot[tid * 4 + 1] = ex + t0 + t1;
        tot[tid * 4 + 2] = ex + t0 + t1 + t2;
        tot[tid * 4 + 3] = ex + s;
    } else if (cntZ) {
        for (int i = tid - 64; i < WAVES * 256; i += 1024 - 64) cntZ[i] = 0;
    }
    __syncthreads();
    for (int i = tid; i < WAVES * 256; i += 1024) {
        int d = i & 255;
        unsigned db = (d == 0) ? 0u : tot[d - 1];
        cntC[i] += db;
    }
    __syncthreads();
}

__global__ __launch_bounds__(1024) void k_sort(
    const ushort* __restrict__ sm2TP,    // 181 x SNP u16 keys (padded)
    const float* __restrict__ WdOut,     // 181 x PP
    float* __restrict__ out)             // 181
{
    __shared__ ushort keysL[SNP];           // 48 KiB
    __shared__ unsigned cntA[WAVES * 256];  // 16 KiB
    __shared__ unsigned cntB[WAVES * 256];  // 16 KiB
    __shared__ unsigned tot[256];
    __shared__ float red[WAVES];

    const int tid  = threadIdx.x;
    const int wave = tid >> 6;
    const int lane = tid & 63;
    const int k    = blockIdx.x;

    const ushort* rowU = sm2TP + (long)k * SNP;
    const float* wrow  = WdOut + (long)k * PP;

    const int base_idx = wave * WCHUNK + lane;
    const int wbase = wave * 256;
    const unsigned long long lt_mask = (1ull << lane) - 1ull;

    for (int i = tid; i < WAVES * 256; i += 1024) cntA[i] = 0;
    __syncthreads();

    // ---- count0: low byte, uniform over SNP ----
    for (int j = 0; j < 24; ++j) {
        unsigned u = rowU[base_idx + j * 64];
        atomicAdd(&cntA[wbase + (u & 255u)], 1u);
    }
    __syncthreads();
    scan_hist(cntA, cntB, tot, tid);   // also zeroes cntB

    // ---- scatter0: G -> LDS on low byte, fused count1 (high byte) ----
    for (int j = 0; j < 24; ++j) {
        unsigned u = rowU[base_idx + j * 64];
        unsigned d = u & 255u;
        unsigned long long mm = matchany8(d);
        int leader = __ffsll(mm) - 1;
        unsigned myrank = (unsigned)__popcll(mm & lt_mask);
        unsigned old = 0;
        if (lane == leader)
            old = atomicAdd(&cntA[wbase + d], (unsigned)__popcll(mm));
        old = (unsigned)__shfl((int)old, leader, 64);
        unsigned dest = old + myrank;
        keysL[dest] = (ushort)u;
        atomicAdd(&cntB[(dest / WCHUNK) * 256 + (u >> 8)], 1u);
    }
    __syncthreads();
    scan_hist(cntB, (unsigned*)0, tot, tid);

    // ---- scatter1: LDS -> fused dot on high byte (pads -> dest >= PP) ----
    float local = 0.f;
    for (int j = 0; j < 24; ++j) {
        unsigned u = keysL[base_idx + j * 64];
        unsigned d = u >> 8;
        unsigned long long mm = matchany8(d);
        int leader = __ffsll(mm) - 1;
        unsigned myrank = (unsigned)__popcll(mm & lt_mask);
        unsigned old = 0;
        if (lane == leader)
            old = atomicAdd(&cntB[wbase + d], (unsigned)__popcll(mm));
        old = (unsigned)__shfl((int)old, leader, 64);
        unsigned dest = old + myrank;
        if (dest < PP) {
            unsigned raw16 = (u & 0x8000u) ? (u & 0x7FFFu) : ((~u) & 0xFFFFu);
            local += wrow[dest] * __uint_as_float(raw16 << 16);
        }
    }

#pragma unroll
    for (int off = 32; off > 0; off >>= 1)
        local += __shfl_down(local, off, 64);
    if (lane == 0) red[wave] = local;
    __syncthreads();
    if (tid < WAVES) {
        float x = red[tid];
#pragma unroll
        for (int off = 8; off > 0; off >>= 1)
            x += __shfl_down(x, off, 64);
        if (tid == 0) out[k] = x;
    }
}

// ---------------------------------------------------------------------------
extern "C" void kernel_launch(void* const* d_in, const int* in_sizes, int n_in,
                              void* d_out, int out_size, void* d_ws, size_t ws_size,
                              hipStream_t stream) {
    const float* M      = (const float*)d_in[0];
    const float* Ws_in  = (const float*)d_in[1];
    const float* Wd_in  = (const float*)d_in[2];
    const float* Ws_out = (const float*)d_in[3];
    const float* Wd_out = (const float*)d_in[4];
    float* out = (float*)d_out;

    // workspace layout (18.4 MB, well under the 35.7 MB used previously):
    // [0, 9.36 MB):    vecB (PP x 192 bf16)
    // [9.36, 18.26):   sm2TP (181 x SNP u16 keys)
    // [18.26, +74KB):  Abf (192 x 192 bf16)
    char* ws = (char*)d_ws;
    ushort* vecB  = (ushort*)ws;
    ushort* sm2TP = (ushort*)(ws + (size_t)PP * VLD * 2);
    ushort* Abf   = (ushort*)(ws + (size_t)PP * VLD * 2 + (size_t)KK * SNP * 2);

    k_inner<<<1280, 256, 0, stream>>>(M, Ws_in, Wd_in, Ws_out, Abf, vecB);

    k_gemm<<<(SNP / 64) * 2, 256, 0, stream>>>(vecB, Abf, sm2TP);

    k_sort<<<KK, 1024, 0, stream>>>(sm2TP, Wd_out, out);
}

// Round 20
// 223.832 us; speedup vs baseline: 1.1626x; 1.0092x over previous
//
#include <hip/hip_runtime.h>
#include <hip/hip_bf16.h>

#define DIMK 3
#define NPTS 30
#define KK   181
#define PP   24360
#define DEMB 190
#define VLD  192   // padded vec row stride (bf16 elements)
#define SNP  24576 // padded row length = 16*1536 (sort rows AND sm2T stride)

typedef __attribute__((ext_vector_type(8))) short bf16x8;
typedef __attribute__((ext_vector_type(4))) float f32x4;

__device__ __forceinline__ ushort f2bf(float f) {
    unsigned u = __float_as_uint(f);
    u += 0x7FFFu + ((u >> 16) & 1u);
    return (ushort)(u >> 16);
}

// ---------------------------------------------------------------------------
// Kernel 1: per-permutation inner embed -> vec (PP x VLD, bf16)
// Round-20: SAME per-wave code/LDS as r14/r18 (one sort array per lane —
// iron law), but 1024-thread blocks: the 27.6 KB LDS is amortized over 16
// waves instead of 4 -> 2 blocks/CU x 55 KB -> 32 waves/CU (100% nominal,
// was 20). launch_bounds(1024,8): VGPR cap 64 >= measured live 44.
// Persistent grid 512 blocks = 8192 waves; chunk stream counts 2731/2731/2730.
// k_prep (Ws_out -> Abf bf16) folded into preamble.
// ---------------------------------------------------------------------------
__global__ __launch_bounds__(1024, 8) void k_inner(
    const float* __restrict__ M,      // 3 x 30
    const float* __restrict__ Ws_in,  // 181 x 3
    const float* __restrict__ Wd_in,  // 181 x 27
    const float* __restrict__ Wout,   // 181 x 190
    ushort* __restrict__ Abf,         // 192 x 192 bf16 out
    ushort* __restrict__ vec)         // PP x VLD (bf16)
{
    __shared__ float Gs[NPTS * 32];
    __shared__ float WsS[192 * 3];
    __shared__ float WdS[192 * 28];

    const int tid = threadIdx.x;

    {
        int gid = blockIdx.x * 1024 + tid;
        if (gid < 192 * 192) {
            int k = gid / 192, d = gid - k * 192;
            Abf[gid] = (k < KK && d < DEMB) ? f2bf(Wout[k * DEMB + d]) : (ushort)0;
        }
    }

    for (int i = tid; i < 192 * 3; i += 1024) WsS[i] = (i < KK * 3) ? Ws_in[i] : 0.f;
    for (int i = tid; i < 192 * 28; i += 1024) {
        int k = i / 28, m = i - k * 28;
        WdS[i] = (k < KK && m < 27) ? Wd_in[k * 27 + m] : 0.f;
    }
    for (int e = tid; e < NPTS * 32; e += 1024) {
        int a = e >> 5, b = e & 31;
        Gs[e] = (b < NPTS)
            ? (M[a] * M[b] + M[NPTS + a] * M[NPTS + b] + M[2 * NPTS + a] * M[2 * NPTS + b])
            : 0.f;
    }
    __syncthreads();

    const int wave = tid >> 6;
    const int lane = tid & 63;
    const int wid = blockIdx.x * 16 + wave;   // 0..8191
    const int chunk = wid % 3;
    const int pstream = wid / 3;              // 0..2730
    const int nstream = (chunk == 2) ? 2730 : 2731;
    const int k = chunk * 64 + lane;

    const float INF = __builtin_inff();
    const bool kvalid = (k < KK);
    const float w0 = WsS[k * 3 + 0];
    const float w1 = WsS[k * 3 + 1];
    const float w2 = WsS[k * 3 + 2];
    const float* wd = WdS + k * 28;

    for (int p = pstream; p < PP; p += nstream) {
        int i0 = p / 812;            // 812 = 29*28
        int r  = p - i0 * 812;
        int i1 = r / 28;
        int i2 = r - i1 * 28;
        int c0 = i0;
        int c1 = i1 + (i1 >= c0 ? 1 : 0);
        int lo = min(c0, c1), hi = max(c0, c1);
        int c2 = i2;
        if (c2 >= lo) c2++;
        if (c2 >= hi) c2++;

        ushort* vrow = vec + (long)p * VLD;

        if (chunk == 0 && lane < 9) {
            int i = lane / 3, j = lane % 3;
            int ci = (i == 0) ? c0 : ((i == 1) ? c1 : c2);
            int cj = (j == 0) ? c0 : ((j == 1) ? c1 : c2);
            vrow[lane] = f2bf(Gs[(ci << 5) + cj]);
        }

        const float* g0 = Gs + (c0 << 5);
        const float* g1 = Gs + (c1 << 5);
        const float* g2 = Gs + (c2 << 5);
        const unsigned xmask = (1u << c0) | (1u << c1) | (1u << c2);

        float v[32];
#pragma unroll
        for (int q = 0; q < 8; ++q) {
            float4 x0 = *(const float4*)&g0[q * 4];
            float4 x1 = *(const float4*)&g1[q * 4];
            float4 x2 = *(const float4*)&g2[q * 4];
            int j0 = q * 4;
            if (j0 + 0 < NPTS) { float val = w0 * x0.x + w1 * x1.x + w2 * x2.x;
                v[j0 + 0] = ((xmask >> (j0 + 0)) & 1u) ? INF : val; }
            if (j0 + 1 < NPTS) { float val = w0 * x0.y + w1 * x1.y + w2 * x2.y;
                v[j0 + 1] = ((xmask >> (j0 + 1)) & 1u) ? INF : val; }
            if (j0 + 2 < NPTS) { float val = w0 * x0.z + w1 * x1.z + w2 * x2.z;
                v[j0 + 2] = ((xmask >> (j0 + 2)) & 1u) ? INF : val; }
            if (j0 + 3 < NPTS) { float val = w0 * x0.w + w1 * x1.w + w2 * x2.w;
                v[j0 + 3] = ((xmask >> (j0 + 3)) & 1u) ? INF : val; }
        }
        v[30] = INF;
        v[31] = INF;

        // Batcher odd-even mergesort, n=32, ascending
#pragma unroll
        for (int pw = 1; pw < 32; pw <<= 1) {
#pragma unroll
            for (int kk = pw; kk >= 1; kk >>= 1) {
#pragma unroll
                for (int j = kk % pw; j + kk < 32; j += 2 * kk) {
#pragma unroll
                    for (int i = 0; i < kk; ++i) {
                        int a = i + j, b = i + j + kk;
                        if (a / (pw * 2) == b / (pw * 2)) {
                            float x = v[a], y = v[b];
                            v[a] = fminf(x, y);
                            v[b] = fmaxf(x, y);
                        }
                    }
                }
            }
        }

        if (kvalid) {
            v[27] = 0.f;
            float emb = 0.f;
#pragma unroll
            for (int q = 0; q < 7; ++q) {
                float4 w4 = *(const float4*)&wd[q * 4];
                emb += w4.x * v[q * 4] + w4.y * v[q * 4 + 1]
                     + w4.z * v[q * 4 + 2] + w4.w * v[q * 4 + 3];
            }
            vrow[9 + k] = f2bf(emb);
        } else if (k < 183) {
            vrow[9 + k] = 0;
        }
    }
}

// ---------------------------------------------------------------------------
// Kernel 2: sm2TP[k][p] via bf16 MFMA, no LDS, 16-bit encoded-key stores
// [r19 base]. Round-20: kt split into QUARTERS (3 kt/block) -> grid 1536,
// 24 waves/CU (was 12; kernel is latency-bound, grid-starved). vecB re-reads
// are L2-hot.
// ---------------------------------------------------------------------------
__global__ __launch_bounds__(256) void k_gemm(
    const ushort* __restrict__ vecB,  // PP x 192 bf16
    const ushort* __restrict__ Abf,   // 192 x 192 bf16
    ushort* __restrict__ sm2TP)       // 181 x SNP u16 encoded keys
{
    const int tid  = threadIdx.x;
    const int bid  = blockIdx.x;
    const int tile = bid >> 2;        // p-tile (64 p's)
    const int qtr  = bid & 3;         // kt quarter: 3 kt each
    const int wave = tid >> 6;
    const int lane = tid & 63;
    const int n = lane & 15;
    const int quad = lane >> 4;
    const int p = tile * 64 + wave * 16 + n;   // < SNP by grid construction

    bf16x8 bfrag[6];
    if (p < PP) {
        const ushort* row = vecB + (long)p * VLD;
#pragma unroll
        for (int kc = 0; kc < 6; ++kc)
            bfrag[kc] = *(const bf16x8*)&row[kc * 32 + quad * 8];
    } else {
        bf16x8 z = {0, 0, 0, 0, 0, 0, 0, 0};
#pragma unroll
        for (int kc = 0; kc < 6; ++kc) bfrag[kc] = z;
    }

#pragma unroll
    for (int i = 0; i < 3; ++i) {
        const int kt = qtr * 3 + i;
        f32x4 acc = {0.f, 0.f, 0.f, 0.f};
        const ushort* arow = Abf + (kt * 16 + n) * 192;
#pragma unroll
        for (int kc = 0; kc < 6; ++kc) {
            bf16x8 afrag = *(const bf16x8*)&arow[kc * 32 + quad * 8];
            acc = __builtin_amdgcn_mfma_f32_16x16x32_bf16(afrag, bfrag[kc], acc, 0, 0, 0);
        }
        int k0 = kt * 16 + quad * 4;
#pragma unroll
        for (int r = 0; r < 4; ++r) {
            int kg = k0 + r;
            if (kg < KK) {
                unsigned e;
                if (p < PP) {
                    unsigned u = __float_as_uint(acc[r]);
                    u = (u & 0x80000000u) ? ~u : (u | 0x80000000u);
                    e = (u + 0x8000u) >> 16;     // RTN 16-bit monotone key
                } else {
                    e = 0xFFFFu;                 // pad sorts strictly last
                }
                sm2TP[(long)kg * SNP + p] = (ushort)e;
            }
        }
    }
}

// ---------------------------------------------------------------------------
// Kernel 3: per-k radix sort on 16-bit keys, 2 x 8-bit passes, 3 traversals,
// no global intermediate [frozen, r19].
// ---------------------------------------------------------------------------
#define WAVES  16
#define WCHUNK 1536

__device__ __forceinline__ unsigned long long matchany8(unsigned d) {
    unsigned long long m = ~0ull;
#pragma unroll
    for (int b = 0; b < 8; ++b) {
        unsigned bit = (d >> b) & 1u;
        unsigned long long bal = __ballot(bit);
        m &= bit ? bal : ~bal;
    }
    return m;
}

__device__ __forceinline__ void scan_hist(unsigned* cntC, unsigned* cntZ,
                                          unsigned* tot, int tid) {
    if (tid < 256) {
        unsigned run = 0;
        for (int w = 0; w < WAVES; ++w) {
            unsigned t = cntC[w * 256 + tid];
            cntC[w * 256 + tid] = run;
            run += t;
        }
        tot[tid] = run;
    }
    __syncthreads();
    if (tid < 64) {
        unsigned t0 = tot[tid * 4], t1 = tot[tid * 4 + 1];
        unsigned t2 = tot[tid * 4 + 2], t3 = tot[tid * 4 + 3];
        unsigned s = t0 + t1 + t2 + t3;
        unsigned sc = s;
#pragma unroll
        for (int off = 1; off < 64; off <<= 1) {
            unsigned o = (unsigned)__shfl_up((int)sc, off, 64);
            if (tid >= off) sc += o;
        }
        unsigned ex = sc - s;
        tot[tid * 4]     = ex + t0;
        tot[tid * 4 + 1] = ex + t0 + t1;
        tot[tid * 4 + 2] = ex + t0 + t1 + t2;
        tot[tid * 4 + 3] = ex + s;
    } else if (cntZ) {
        for (int i = tid - 64; i < WAVES * 256; i += 1024 - 64) cntZ[i] = 0;
    }
    __syncthreads();
    for (int i = tid; i < WAVES * 256; i += 1024) {
        int d = i & 255;
        unsigned db = (d == 0) ? 0u : tot[d - 1];
        cntC[i] += db;
    }
    __syncthreads();
}

__global__ __launch_bounds__(1024) void k_sort(
    const ushort* __restrict__ sm2TP,    // 181 x SNP u16 keys (padded)
    const float* __restrict__ WdOut,     // 181 x PP
    float* __restrict__ out)             // 181
{
    __shared__ ushort keysL[SNP];           // 48 KiB
    __shared__ unsigned cntA[WAVES * 256];  // 16 KiB
    __shared__ unsigned cntB[WAVES * 256];  // 16 KiB
    __shared__ unsigned tot[256];
    __shared__ float red[WAVES];

    const int tid  = threadIdx.x;
    const int wave = tid >> 6;
    const int lane = tid & 63;
    const int k    = blockIdx.x;

    const ushort* rowU = sm2TP + (long)k * SNP;
    const float* wrow  = WdOut + (long)k * PP;

    const int base_idx = wave * WCHUNK + lane;
    const int wbase = wave * 256;
    const unsigned long long lt_mask = (1ull << lane) - 1ull;

    for (int i = tid; i < WAVES * 256; i += 1024) cntA[i] = 0;
    __syncthreads();

    // ---- count0: low byte, uniform over SNP ----
    for (int j = 0; j < 24; ++j) {
        unsigned u = rowU[base_idx + j * 64];
        atomicAdd(&cntA[wbase + (u & 255u)], 1u);
    }
    __syncthreads();
    scan_hist(cntA, cntB, tot, tid);   // also zeroes cntB

    // ---- scatter0: G -> LDS on low byte, fused count1 (high byte) ----
    for (int j = 0; j < 24; ++j) {
        unsigned u = rowU[base_idx + j * 64];
        unsigned d = u & 255u;
        unsigned long long mm = matchany8(d);
        int leader = __ffsll(mm) - 1;
        unsigned myrank = (unsigned)__popcll(mm & lt_mask);
        unsigned old = 0;
        if (lane == leader)
            old = atomicAdd(&cntA[wbase + d], (unsigned)__popcll(mm));
        old = (unsigned)__shfl((int)old, leader, 64);
        unsigned dest = old + myrank;
        keysL[dest] = (ushort)u;
        atomicAdd(&cntB[(dest / WCHUNK) * 256 + (u >> 8)], 1u);
    }
    __syncthreads();
    scan_hist(cntB, (unsigned*)0, tot, tid);

    // ---- scatter1: LDS -> fused dot on high byte (pads -> dest >= PP) ----
    float local = 0.f;
    for (int j = 0; j < 24; ++j) {
        unsigned u = keysL[base_idx + j * 64];
        unsigned d = u >> 8;
        unsigned long long mm = matchany8(d);
        int leader = __ffsll(mm) - 1;
        unsigned myrank = (unsigned)__popcll(mm & lt_mask);
        unsigned old = 0;
        if (lane == leader)
            old = atomicAdd(&cntB[wbase + d], (unsigned)__popcll(mm));
        old = (unsigned)__shfl((int)old, leader, 64);
        unsigned dest = old + myrank;
        if (dest < PP) {
            unsigned raw16 = (u & 0x8000u) ? (u & 0x7FFFu) : ((~u) & 0xFFFFu);
            local += wrow[dest] * __uint_as_float(raw16 << 16);
        }
    }

#pragma unroll
    for (int off = 32; off > 0; off >>= 1)
        local += __shfl_down(local, off, 64);
    if (lane == 0) red[wave] = local;
    __syncthreads();
    if (tid < WAVES) {
        float x = red[tid];
#pragma unroll
        for (int off = 8; off > 0; off >>= 1)
            x += __shfl_down(x, off, 64);
        if (tid == 0) out[k] = x;
    }
}

// ---------------------------------------------------------------------------
extern "C" void kernel_launch(void* const* d_in, const int* in_sizes, int n_in,
                              void* d_out, int out_size, void* d_ws, size_t ws_size,
                              hipStream_t stream) {
    const float* M      = (const float*)d_in[0];
    const float* Ws_in  = (const float*)d_in[1];
    const float* Wd_in  = (const float*)d_in[2];
    const float* Ws_out = (const float*)d_in[3];
    const float* Wd_out = (const float*)d_in[4];
    float* out = (float*)d_out;

    // workspace layout (18.4 MB):
    // [0, 9.36 MB):    vecB (PP x 192 bf16)
    // [9.36, 18.26):   sm2TP (181 x SNP u16 keys)
    // [18.26, +74KB):  Abf (192 x 192 bf16)
    char* ws = (char*)d_ws;
    ushort* vecB  = (ushort*)ws;
    ushort* sm2TP = (ushort*)(ws + (size_t)PP * VLD * 2);
    ushort* Abf   = (ushort*)(ws + (size_t)PP * VLD * 2 + (size_t)KK * SNP * 2);

    k_inner<<<512, 1024, 0, stream>>>(M, Ws_in, Wd_in, Ws_out, Abf, vecB);

    k_gemm<<<(SNP / 64) * 4, 256, 0, stream>>>(vecB, Abf, sm2TP);

    k_sort<<<KK, 1024, 0, stream>>>(sm2TP, Wd_out, out);
}

// Round 21
// 219.139 us; speedup vs baseline: 1.1875x; 1.0214x over previous
//
#include <hip/hip_runtime.h>
#include <hip/hip_bf16.h>

#define DIMK 3
#define NPTS 30
#define KK   181
#define PP   24360
#define DEMB 190
#define VLD  192   // padded vec row stride (bf16 elements)
#define SNP  24576 // padded row length = 16*1536 (sort rows AND sm2T stride)

typedef __attribute__((ext_vector_type(8))) short bf16x8;
typedef __attribute__((ext_vector_type(4))) float f32x4;

__device__ __forceinline__ ushort f2bf(float f) {
    unsigned u = __float_as_uint(f);
    u += 0x7FFFu + ((u >> 16) & 1u);
    return (ushort)(u >> 16);
}

// ---------------------------------------------------------------------------
// Kernel 1: per-permutation inner embed -> vec (PP x VLD, bf16)
// Round-21: identical to r20 except __launch_bounds__(1024, 2). r20's (1024,8)
// made the allocator target 32 VGPRs and spill v[32] to scratch (WRITE 24 MB,
// FETCH 5.3 MB, occupancy capped at 1 block/CU by scratch backing). With cap
// 256 the compiler returns to its natural ~44 VGPRs (proven r14/r18); at 44
// (<64) HW still allows 8 waves/EU -> 2 x 1024-thread blocks/CU = 32 waves.
// ---------------------------------------------------------------------------
__global__ __launch_bounds__(1024, 2) void k_inner(
    const float* __restrict__ M,      // 3 x 30
    const float* __restrict__ Ws_in,  // 181 x 3
    const float* __restrict__ Wd_in,  // 181 x 27
    const float* __restrict__ Wout,   // 181 x 190
    ushort* __restrict__ Abf,         // 192 x 192 bf16 out
    ushort* __restrict__ vec)         // PP x VLD (bf16)
{
    __shared__ float Gs[NPTS * 32];
    __shared__ float WsS[192 * 3];
    __shared__ float WdS[192 * 28];

    const int tid = threadIdx.x;

    {
        int gid = blockIdx.x * 1024 + tid;
        if (gid < 192 * 192) {
            int k = gid / 192, d = gid - k * 192;
            Abf[gid] = (k < KK && d < DEMB) ? f2bf(Wout[k * DEMB + d]) : (ushort)0;
        }
    }

    for (int i = tid; i < 192 * 3; i += 1024) WsS[i] = (i < KK * 3) ? Ws_in[i] : 0.f;
    for (int i = tid; i < 192 * 28; i += 1024) {
        int k = i / 28, m = i - k * 28;
        WdS[i] = (k < KK && m < 27) ? Wd_in[k * 27 + m] : 0.f;
    }
    for (int e = tid; e < NPTS * 32; e += 1024) {
        int a = e >> 5, b = e & 31;
        Gs[e] = (b < NPTS)
            ? (M[a] * M[b] + M[NPTS + a] * M[NPTS + b] + M[2 * NPTS + a] * M[2 * NPTS + b])
            : 0.f;
    }
    __syncthreads();

    const int wave = tid >> 6;
    const int lane = tid & 63;
    const int wid = blockIdx.x * 16 + wave;   // 0..8191
    const int chunk = wid % 3;
    const int pstream = wid / 3;              // 0..2730
    const int nstream = (chunk == 2) ? 2730 : 2731;
    const int k = chunk * 64 + lane;

    const float INF = __builtin_inff();
    const bool kvalid = (k < KK);
    const float w0 = WsS[k * 3 + 0];
    const float w1 = WsS[k * 3 + 1];
    const float w2 = WsS[k * 3 + 2];
    const float* wd = WdS + k * 28;

    for (int p = pstream; p < PP; p += nstream) {
        int i0 = p / 812;            // 812 = 29*28
        int r  = p - i0 * 812;
        int i1 = r / 28;
        int i2 = r - i1 * 28;
        int c0 = i0;
        int c1 = i1 + (i1 >= c0 ? 1 : 0);
        int lo = min(c0, c1), hi = max(c0, c1);
        int c2 = i2;
        if (c2 >= lo) c2++;
        if (c2 >= hi) c2++;

        ushort* vrow = vec + (long)p * VLD;

        if (chunk == 0 && lane < 9) {
            int i = lane / 3, j = lane % 3;
            int ci = (i == 0) ? c0 : ((i == 1) ? c1 : c2);
            int cj = (j == 0) ? c0 : ((j == 1) ? c1 : c2);
            vrow[lane] = f2bf(Gs[(ci << 5) + cj]);
        }

        const float* g0 = Gs + (c0 << 5);
        const float* g1 = Gs + (c1 << 5);
        const float* g2 = Gs + (c2 << 5);
        const unsigned xmask = (1u << c0) | (1u << c1) | (1u << c2);

        float v[32];
#pragma unroll
        for (int q = 0; q < 8; ++q) {
            float4 x0 = *(const float4*)&g0[q * 4];
            float4 x1 = *(const float4*)&g1[q * 4];
            float4 x2 = *(const float4*)&g2[q * 4];
            int j0 = q * 4;
            if (j0 + 0 < NPTS) { float val = w0 * x0.x + w1 * x1.x + w2 * x2.x;
                v[j0 + 0] = ((xmask >> (j0 + 0)) & 1u) ? INF : val; }
            if (j0 + 1 < NPTS) { float val = w0 * x0.y + w1 * x1.y + w2 * x2.y;
                v[j0 + 1] = ((xmask >> (j0 + 1)) & 1u) ? INF : val; }
            if (j0 + 2 < NPTS) { float val = w0 * x0.z + w1 * x1.z + w2 * x2.z;
                v[j0 + 2] = ((xmask >> (j0 + 2)) & 1u) ? INF : val; }
            if (j0 + 3 < NPTS) { float val = w0 * x0.w + w1 * x1.w + w2 * x2.w;
                v[j0 + 3] = ((xmask >> (j0 + 3)) & 1u) ? INF : val; }
        }
        v[30] = INF;
        v[31] = INF;

        // Batcher odd-even mergesort, n=32, ascending
#pragma unroll
        for (int pw = 1; pw < 32; pw <<= 1) {
#pragma unroll
            for (int kk = pw; kk >= 1; kk >>= 1) {
#pragma unroll
                for (int j = kk % pw; j + kk < 32; j += 2 * kk) {
#pragma unroll
                    for (int i = 0; i < kk; ++i) {
                        int a = i + j, b = i + j + kk;
                        if (a / (pw * 2) == b / (pw * 2)) {
                            float x = v[a], y = v[b];
                            v[a] = fminf(x, y);
                            v[b] = fmaxf(x, y);
                        }
                    }
                }
            }
        }

        if (kvalid) {
            v[27] = 0.f;
            float emb = 0.f;
#pragma unroll
            for (int q = 0; q < 7; ++q) {
                float4 w4 = *(const float4*)&wd[q * 4];
                emb += w4.x * v[q * 4] + w4.y * v[q * 4 + 1]
                     + w4.z * v[q * 4 + 2] + w4.w * v[q * 4 + 3];
            }
            vrow[9 + k] = f2bf(emb);
        } else if (k < 183) {
            vrow[9 + k] = 0;
        }
    }
}

// ---------------------------------------------------------------------------
// Kernel 2: sm2TP[k][p] via bf16 MFMA, no LDS, 16-bit encoded-key stores,
// kt quarters (3 kt/block, grid 1536) [frozen, r20]
// ---------------------------------------------------------------------------
__global__ __launch_bounds__(256) void k_gemm(
    const ushort* __restrict__ vecB,  // PP x 192 bf16
    const ushort* __restrict__ Abf,   // 192 x 192 bf16
    ushort* __restrict__ sm2TP)       // 181 x SNP u16 encoded keys
{
    const int tid  = threadIdx.x;
    const int bid  = blockIdx.x;
    const int tile = bid >> 2;        // p-tile (64 p's)
    const int qtr  = bid & 3;         // kt quarter: 3 kt each
    const int wave = tid >> 6;
    const int lane = tid & 63;
    const int n = lane & 15;
    const int quad = lane >> 4;
    const int p = tile * 64 + wave * 16 + n;   // < SNP by grid construction

    bf16x8 bfrag[6];
    if (p < PP) {
        const ushort* row = vecB + (long)p * VLD;
#pragma unroll
        for (int kc = 0; kc < 6; ++kc)
            bfrag[kc] = *(const bf16x8*)&row[kc * 32 + quad * 8];
    } else {
        bf16x8 z = {0, 0, 0, 0, 0, 0, 0, 0};
#pragma unroll
        for (int kc = 0; kc < 6; ++kc) bfrag[kc] = z;
    }

#pragma unroll
    for (int i = 0; i < 3; ++i) {
        const int kt = qtr * 3 + i;
        f32x4 acc = {0.f, 0.f, 0.f, 0.f};
        const ushort* arow = Abf + (kt * 16 + n) * 192;
#pragma unroll
        for (int kc = 0; kc < 6; ++kc) {
            bf16x8 afrag = *(const bf16x8*)&arow[kc * 32 + quad * 8];
            acc = __builtin_amdgcn_mfma_f32_16x16x32_bf16(afrag, bfrag[kc], acc, 0, 0, 0);
        }
        int k0 = kt * 16 + quad * 4;
#pragma unroll
        for (int r = 0; r < 4; ++r) {
            int kg = k0 + r;
            if (kg < KK) {
                unsigned e;
                if (p < PP) {
                    unsigned u = __float_as_uint(acc[r]);
                    u = (u & 0x80000000u) ? ~u : (u | 0x80000000u);
                    e = (u + 0x8000u) >> 16;     // RTN 16-bit monotone key
                } else {
                    e = 0xFFFFu;                 // pad sorts strictly last
                }
                sm2TP[(long)kg * SNP + p] = (ushort)e;
            }
        }
    }
}

// ---------------------------------------------------------------------------
// Kernel 3: per-k radix sort on 16-bit keys, 2 x 8-bit passes, 3 traversals,
// no global intermediate [frozen, r19].
// ---------------------------------------------------------------------------
#define WAVES  16
#define WCHUNK 1536

__device__ __forceinline__ unsigned long long matchany8(unsigned d) {
    unsigned long long m = ~0ull;
#pragma unroll
    for (int b = 0; b < 8; ++b) {
        unsigned bit = (d >> b) & 1u;
        unsigned long long bal = __ballot(bit);
        m &= bit ? bal : ~bal;
    }
    return m;
}

__device__ __forceinline__ void scan_hist(unsigned* cntC, unsigned* cntZ,
                                          unsigned* tot, int tid) {
    if (tid < 256) {
        unsigned run = 0;
        for (int w = 0; w < WAVES; ++w) {
            unsigned t = cntC[w * 256 + tid];
            cntC[w * 256 + tid] = run;
            run += t;
        }
        tot[tid] = run;
    }
    __syncthreads();
    if (tid < 64) {
        unsigned t0 = tot[tid * 4], t1 = tot[tid * 4 + 1];
        unsigned t2 = tot[tid * 4 + 2], t3 = tot[tid * 4 + 3];
        unsigned s = t0 + t1 + t2 + t3;
        unsigned sc = s;
#pragma unroll
        for (int off = 1; off < 64; off <<= 1) {
            unsigned o = (unsigned)__shfl_up((int)sc, off, 64);
            if (tid >= off) sc += o;
        }
        unsigned ex = sc - s;
        tot[tid * 4]     = ex + t0;
        tot[tid * 4 + 1] = ex + t0 + t1;
        tot[tid * 4 + 2] = ex + t0 + t1 + t2;
        tot[tid * 4 + 3] = ex + s;
    } else if (cntZ) {
        for (int i = tid - 64; i < WAVES * 256; i += 1024 - 64) cntZ[i] = 0;
    }
    __syncthreads();
    for (int i = tid; i < WAVES * 256; i += 1024) {
        int d = i & 255;
        unsigned db = (d == 0) ? 0u : tot[d - 1];
        cntC[i] += db;
    }
    __syncthreads();
}

__global__ __launch_bounds__(1024) void k_sort(
    const ushort* __restrict__ sm2TP,    // 181 x SNP u16 keys (padded)
    const float* __restrict__ WdOut,     // 181 x PP
    float* __restrict__ out)             // 181
{
    __shared__ ushort keysL[SNP];           // 48 KiB
    __shared__ unsigned cntA[WAVES * 256];  // 16 KiB
    __shared__ unsigned cntB[WAVES * 256];  // 16 KiB
    __shared__ unsigned tot[256];
    __shared__ float red[WAVES];

    const int tid  = threadIdx.x;
    const int wave = tid >> 6;
    const int lane = tid & 63;
    const int k    = blockIdx.x;

    const ushort* rowU = sm2TP + (long)k * SNP;
    const float* wrow  = WdOut + (long)k * PP;

    const int base_idx = wave * WCHUNK + lane;
    const int wbase = wave * 256;
    const unsigned long long lt_mask = (1ull << lane) - 1ull;

    for (int i = tid; i < WAVES * 256; i += 1024) cntA[i] = 0;
    __syncthreads();

    // ---- count0: low byte, uniform over SNP ----
    for (int j = 0; j < 24; ++j) {
        unsigned u = rowU[base_idx + j * 64];
        atomicAdd(&cntA[wbase + (u & 255u)], 1u);
    }
    __syncthreads();
    scan_hist(cntA, cntB, tot, tid);   // also zeroes cntB

    // ---- scatter0: G -> LDS on low byte, fused count1 (high byte) ----
    for (int j = 0; j < 24; ++j) {
        unsigned u = rowU[base_idx + j * 64];
        unsigned d = u & 255u;
        unsigned long long mm = matchany8(d);
        int leader = __ffsll(mm) - 1;
        unsigned myrank = (unsigned)__popcll(mm & lt_mask);
        unsigned old = 0;
        if (lane == leader)
            old = atomicAdd(&cntA[wbase + d], (unsigned)__popcll(mm));
        old = (unsigned)__shfl((int)old, leader, 64);
        unsigned dest = old + myrank;
        keysL[dest] = (ushort)u;
        atomicAdd(&cntB[(dest / WCHUNK) * 256 + (u >> 8)], 1u);
    }
    __syncthreads();
    scan_hist(cntB, (unsigned*)0, tot, tid);

    // ---- scatter1: LDS -> fused dot on high byte (pads -> dest >= PP) ----
    float local = 0.f;
    for (int j = 0; j < 24; ++j) {
        unsigned u = keysL[base_idx + j * 64];
        unsigned d = u >> 8;
        unsigned long long mm = matchany8(d);
        int leader = __ffsll(mm) - 1;
        unsigned myrank = (unsigned)__popcll(mm & lt_mask);
        unsigned old = 0;
        if (lane == leader)
            old = atomicAdd(&cntB[wbase + d], (unsigned)__popcll(mm));
        old = (unsigned)__shfl((int)old, leader, 64);
        unsigned dest = old + myrank;
        if (dest < PP) {
            unsigned raw16 = (u & 0x8000u) ? (u & 0x7FFFu) : ((~u) & 0xFFFFu);
            local += wrow[dest] * __uint_as_float(raw16 << 16);
        }
    }

#pragma unroll
    for (int off = 32; off > 0; off >>= 1)
        local += __shfl_down(local, off, 64);
    if (lane == 0) red[wave] = local;
    __syncthreads();
    if (tid < WAVES) {
        float x = red[tid];
#pragma unroll
        for (int off = 8; off > 0; off >>= 1)
            x += __shfl_down(x, off, 64);
        if (tid == 0) out[k] = x;
    }
}

// ---------------------------------------------------------------------------
extern "C" void kernel_launch(void* const* d_in, const int* in_sizes, int n_in,
                              void* d_out, int out_size, void* d_ws, size_t ws_size,
                              hipStream_t stream) {
    const float* M      = (const float*)d_in[0];
    const float* Ws_in  = (const float*)d_in[1];
    const float* Wd_in  = (const float*)d_in[2];
    const float* Ws_out = (const float*)d_in[3];
    const float* Wd_out = (const float*)d_in[4];
    float* out = (float*)d_out;

    // workspace layout (18.4 MB):
    // [0, 9.36 MB):    vecB (PP x 192 bf16)
    // [9.36, 18.26):   sm2TP (181 x SNP u16 keys)
    // [18.26, +74KB):  Abf (192 x 192 bf16)
    char* ws = (char*)d_ws;
    ushort* vecB  = (ushort*)ws;
    ushort* sm2TP = (ushort*)(ws + (size_t)PP * VLD * 2);
    ushort* Abf   = (ushort*)(ws + (size_t)PP * VLD * 2 + (size_t)KK * SNP * 2);

    k_inner<<<512, 1024, 0, stream>>>(M, Ws_in, Wd_in, Ws_out, Abf, vecB);

    k_gemm<<<(SNP / 64) * 4, 256, 0, stream>>>(vecB, Abf, sm2TP);

    k_sort<<<KK, 1024, 0, stream>>>(sm2TP, Wd_out, out);
}